// Round 3
// baseline (136.445 us; speedup 1.0000x reference)
//
#include <hip/hip_runtime.h>
#include <hip/hip_bf16.h>

// CoarsenLattice forward: out[Nc,128] = gather(fine, nbr)[Nc, 9*64] @ W[576,128]
// Round 3: latency-decoupled design.
//  - A: direct-to-register gather, per-wave-private (wave owns 16 rows x 128 cols),
//    indices hoisted to registers, prefetched 1 neighbor ahead, gathers stay in
//    flight ACROSS the barrier (counted vmcnt).
//  - W: bf16, pre-swizzled in workspace; staged per-fe via global_load_lds
//    (dwordx4) into double-buffered LDS; ds_read_b128 conflict-free via XOR swizzle.
//  - One barrier per fe (vs two before), no LDS for A, no LDS for indices.

#define N_FINE   1048576
#define N_COARSE 262144
#define VAL_DIM  64
#define FE       9
#define NF       128
#define BM       128              // 8 waves * 16 rows
#define THREADS  512

typedef __attribute__((ext_vector_type(8))) short bf16x8;
typedef __attribute__((ext_vector_type(4))) float f32x4;

__device__ __forceinline__ unsigned short f2bf(float f) {
    unsigned u = __float_as_uint(f);
    return (unsigned short)((u + 0x7FFFu + ((u >> 16) & 1u)) >> 16);
}

// W prep: wTswz is FE tiles of 8192 ushorts (16 KB). Within a tile, the byte
// stream is the LDS image: logical chunk (col,kc) lives at byte
// col*128 + ((kc*16) ^ ((col&7)<<4)). We iterate dest-linear and unswizzle.
__global__ void prep_wt_kernel(const float* __restrict__ w,
                               unsigned short* __restrict__ wTswz) {
    int i = blockIdx.x * 256 + threadIdx.x;     // over FE*8192 = 73728 ushorts
    if (i >= FE * 8192) return;
    int fe   = i >> 13;
    int r    = i & 8191;
    int byte = r * 2;
    int col  = byte >> 7;                       // 0..127
    int b0   = (byte & 127) ^ ((col & 7) << 4); // unswizzled byte within row
    int k    = fe * 64 + (b0 >> 1);             // kc*8 + e
    wTswz[i] = f2bf(w[(size_t)k * NF + col]);
}

__launch_bounds__(THREADS, 4)
__global__ void coarsen_kernel(const float* __restrict__ fine,
                               const int* __restrict__ nbr,
                               const unsigned short* __restrict__ wTswz,
                               float* __restrict__ out) {
    __shared__ __align__(16) unsigned short sW[2][8192];   // 2 x 16 KB

    const int t    = threadIdx.x;
    const int wave = t >> 6;
    const int lane = t & 63;
    const int l15  = lane & 15;
    const int lhi  = lane >> 4;
    const int bRow = blockIdx.x * BM;
    const int myRow = bRow + wave * 16 + l15;   // the fine-lattice row this lane gathers

    // hoist all 9 neighbor indices into registers (kills the dependent-load chain)
    int idx[FE];
    {
        const int* nb = nbr + (size_t)myRow * FE;
#pragma unroll
        for (int f = 0; f < FE; ++f) idx[f] = nb[f];
    }

    f32x4 acc[8];
#pragma unroll
    for (int i = 0; i < 8; ++i) acc[i] = (f32x4)0.0f;

    float4 pa[4];        // prefetched A row chunk (fe+1)
    bf16x8 af0, af1;     // current A fragments (ks=0,1)

#define LOAD_A(fe_) do {                                                   \
    const float* rp_ = fine + (size_t)idx[fe_] * VAL_DIM + lhi * 8;        \
    pa[0] = *(const float4*)(rp_);                                         \
    pa[1] = *(const float4*)(rp_ + 4);                                     \
    pa[2] = *(const float4*)(rp_ + 32);                                    \
    pa[3] = *(const float4*)(rp_ + 36);                                    \
} while (0)

#define STAGE_W(fe_, buf_) do {                                            \
    const char* gs_ = (const char*)wTswz + (size_t)(fe_) * 16384;          \
    char* ls_ = (char*)&sW[buf_][0];                                       \
    __builtin_amdgcn_global_load_lds(                                      \
        (const __attribute__((address_space(1))) void*)(gs_ + t * 16),     \
        (__attribute__((address_space(3))) void*)(ls_ + t * 16), 16, 0, 0);\
    __builtin_amdgcn_global_load_lds(                                      \
        (const __attribute__((address_space(1))) void*)(gs_ + 8192 + t * 16), \
        (__attribute__((address_space(3))) void*)(ls_ + 8192 + t * 16), 16, 0, 0); \
} while (0)

#define CONV_A() do {                                                      \
    union { bf16x8 v; unsigned short u[8]; } c0_, c1_;                     \
    c0_.u[0] = f2bf(pa[0].x); c0_.u[1] = f2bf(pa[0].y);                    \
    c0_.u[2] = f2bf(pa[0].z); c0_.u[3] = f2bf(pa[0].w);                    \
    c0_.u[4] = f2bf(pa[1].x); c0_.u[5] = f2bf(pa[1].y);                    \
    c0_.u[6] = f2bf(pa[1].z); c0_.u[7] = f2bf(pa[1].w);                    \
    c1_.u[0] = f2bf(pa[2].x); c1_.u[1] = f2bf(pa[2].y);                    \
    c1_.u[2] = f2bf(pa[2].z); c1_.u[3] = f2bf(pa[2].w);                    \
    c1_.u[4] = f2bf(pa[3].x); c1_.u[5] = f2bf(pa[3].y);                    \
    c1_.u[6] = f2bf(pa[3].z); c1_.u[7] = f2bf(pa[3].w);                    \
    af0 = c0_.v; af1 = c1_.v;                                              \
} while (0)

    // ---- prologue: stage fe=0 ----
    STAGE_W(0, 0);
    LOAD_A(0);
    asm volatile("s_waitcnt vmcnt(0)" ::: "memory");
    __syncthreads();

#pragma unroll
    for (int fe = 0; fe < FE; ++fe) {
        const int buf = fe & 1;
        CONV_A();                              // consumes pa(fe); compiler waits its own loads
        if (fe + 1 < FE) {
            STAGE_W(fe + 1, buf ^ 1);          // issue glds FIRST (oldest in vmcnt queue)
            LOAD_A(fe + 1);                    // then the 4 A gathers (stay in flight)
        }
        // compute fe from sW[buf]
#pragma unroll
        for (int ks = 0; ks < 2; ++ks) {
            const bf16x8 a = ks ? af1 : af0;
            const int off = ks * 64 + lhi * 16;
#pragma unroll
            for (int fn = 0; fn < 8; ++fn) {
                const int col = fn * 16 + l15;
                const bf16x8 b = *(const bf16x8*)(
                    (const char*)&sW[buf][0] + col * 128 + (off ^ ((col & 7) << 4)));
                acc[fn] = __builtin_amdgcn_mfma_f32_16x16x32_bf16(a, b, acc[fn], 0, 0, 0);
            }
        }
        if (fe + 1 < FE) {
            // drain only the 2 staging loads; leave the 4 A gathers in flight
            asm volatile("s_waitcnt vmcnt(4)" ::: "memory");
            __syncthreads();
        }
    }

    // ---- epilogue: C[row = lhi*4+j][col = l15] per 16x16 frag ----
#pragma unroll
    for (int fn = 0; fn < 8; ++fn)
#pragma unroll
        for (int j = 0; j < 4; ++j) {
            const int row = bRow + wave * 16 + lhi * 4 + j;
            const int col = fn * 16 + l15;
            out[(size_t)row * NF + col] = acc[fn][j];
        }

#undef LOAD_A
#undef STAGE_W
#undef CONV_A
}

extern "C" void kernel_launch(void* const* d_in, const int* in_sizes, int n_in,
                              void* d_out, int out_size, void* d_ws, size_t ws_size,
                              hipStream_t stream) {
    const float* fine = (const float*)d_in[0];
    const int*   nbr  = (const int*)d_in[1];
    const float* w    = (const float*)d_in[2];
    float* out = (float*)d_out;

    unsigned short* wTswz = (unsigned short*)d_ws;   // FE*8192 ushorts = 144 KB

    prep_wt_kernel<<<(FE * 8192 + 255) / 256, 256, 0, stream>>>(w, wTswz);
    coarsen_kernel<<<N_COARSE / BM, THREADS, 0, stream>>>(fine, nbr, wTswz, out);
}